// Round 1
// baseline (869.680 us; speedup 1.0000x reference)
//
#include <hip/hip_runtime.h>
#include <math.h>

#define D 128
#define K 128
#define ROWS_PER_BLOCK 64
#define TAU 0.005f

typedef __bf16 bf16x8 __attribute__((ext_vector_type(8)));
typedef float f32x4 __attribute__((ext_vector_type(4)));
typedef unsigned short ushort8v __attribute__((ext_vector_type(8)));

__device__ inline unsigned short f2bf(float f) {
    unsigned u = __float_as_uint(f);
    u += 0x7fffu + ((u >> 16) & 1u);   // RNE
    return (unsigned short)(u >> 16);
}
__device__ inline float bf2f(unsigned short h) {
    return __uint_as_float(((unsigned)h) << 16);
}

// ---------------------------------------------------------------------------
// Prep kernel (1 block): exact ww (pairwise-8 recipe) -> ws[0:128)
// plus W as bf16 hi/lo MFMA B-fragments -> ws+128 (64 chunks x 1024 B).
// Chunk c = (kt*4 + ks)*2 + p; lane l holds W[kt*16 + (l&15)][ks*32 + (l>>4)*8 + j]
// ---------------------------------------------------------------------------
__global__ void vq_prep_kernel(const float* __restrict__ W, float* __restrict__ ws)
{
    const int tid = threadIdx.x;

    if (tid < K) {
        const float* w = W + (size_t)tid * D;
        float r0 = __fmul_rn(w[0], w[0]);
        float r1 = __fmul_rn(w[1], w[1]);
        float r2 = __fmul_rn(w[2], w[2]);
        float r3 = __fmul_rn(w[3], w[3]);
        float r4 = __fmul_rn(w[4], w[4]);
        float r5 = __fmul_rn(w[5], w[5]);
        float r6 = __fmul_rn(w[6], w[6]);
        float r7 = __fmul_rn(w[7], w[7]);
        #pragma unroll 1
        for (int i = 8; i < D; i += 8) {
            r0 = __fadd_rn(r0, __fmul_rn(w[i + 0], w[i + 0]));
            r1 = __fadd_rn(r1, __fmul_rn(w[i + 1], w[i + 1]));
            r2 = __fadd_rn(r2, __fmul_rn(w[i + 2], w[i + 2]));
            r3 = __fadd_rn(r3, __fmul_rn(w[i + 3], w[i + 3]));
            r4 = __fadd_rn(r4, __fmul_rn(w[i + 4], w[i + 4]));
            r5 = __fadd_rn(r5, __fmul_rn(w[i + 5], w[i + 5]));
            r6 = __fadd_rn(r6, __fmul_rn(w[i + 6], w[i + 6]));
            r7 = __fadd_rn(r7, __fmul_rn(w[i + 7], w[i + 7]));
        }
        float a01 = __fadd_rn(r0, r1);
        float a23 = __fadd_rn(r2, r3);
        float a45 = __fadd_rn(r4, r5);
        float a67 = __fadd_rn(r6, r7);
        ws[tid] = __fadd_rn(__fadd_rn(a01, a23), __fadd_rn(a45, a67));
    }

    unsigned short* frag = (unsigned short*)(ws + K);
    #pragma unroll 1
    for (int s = tid; s < 64 * 64; s += 256) {
        const int c  = s >> 6;          // chunk 0..63
        const int l  = s & 63;          // lane slot
        const int p  = c & 1;           // 0 = hi plane, 1 = lo plane
        const int ks = (c >> 1) & 3;
        const int kt = c >> 3;
        const int n  = kt * 16 + (l & 15);
        const int k0 = ks * 32 + (l >> 4) * 8;
        const float* wr = W + (size_t)n * D + k0;
        ushort8v o;
        #pragma unroll
        for (int j = 0; j < 8; j++) {
            const float f = wr[j];
            const unsigned short hi = f2bf(f);
            o[j] = (p == 0) ? hi : f2bf(f - bf2f(hi));
        }
        *(ushort8v*)(frag + (size_t)c * 512 + l * 8) = o;
    }
}

// ---------------------------------------------------------------------------
// Main kernel: 64 rows/block, 4 waves x 16 rows. Distances via bf16 2-term
// split MFMA (a*wa + a*wb + b*wa, fp32 accum). Rows with approx margin < TAU
// re-solved with the exact validated fp32 recipe (matches reference argmin).
// ---------------------------------------------------------------------------
__global__ __launch_bounds__(256, 4) void vq_mfma_kernel(
    const float* __restrict__ z,
    const float* __restrict__ W,
    const float* __restrict__ ws,
    float* __restrict__ out,
    int n_rows)
{
    __shared__ int bestk_s[ROWS_PER_BLOCK];

    const int tid  = threadIdx.x;
    const int wave = tid >> 6;
    const int lane = tid & 63;
    const int lr   = lane & 15;   // A row-in-tile / B,C column-in-tile
    const int lg   = lane >> 4;   // 16-lane group

    const long long blockRow0 = (long long)blockIdx.x * ROWS_PER_BLOCK;

    // ---- A fragments: load 8 floats/ks straight from global z, split to bf16 hi/lo
    const long long rowA  = blockRow0 + wave * 16 + lr;
    const long long rowAc = (rowA < (long long)n_rows) ? rowA : (long long)(n_rows - 1);

    bf16x8 aA[4], aB[4];
    {
        const float* zr = z + rowAc * D + lg * 8;
        #pragma unroll
        for (int ks = 0; ks < 4; ks++) {
            const float4 v0 = *(const float4*)(zr + ks * 32);
            const float4 v1 = *(const float4*)(zr + ks * 32 + 4);
            const float f[8] = {v0.x, v0.y, v0.z, v0.w, v1.x, v1.y, v1.z, v1.w};
            ushort8v ha, hb;
            #pragma unroll
            for (int j = 0; j < 8; j++) {
                const unsigned short hi = f2bf(f[j]);
                ha[j] = hi;
                hb[j] = f2bf(f[j] - bf2f(hi));
            }
            aA[ks] = __builtin_bit_cast(bf16x8, ha);
            aB[ks] = __builtin_bit_cast(bf16x8, hb);
        }
    }

    // ---- MFMA over 8 k-tiles; fold distance + best/2nd tracking per tile ----
    const unsigned short* frag = (const unsigned short*)(ws + K);

    float bd0 = INFINITY, bd1 = INFINITY, bd2 = INFINITY, bd3 = INFINITY;
    float sd0 = INFINITY, sd1 = INFINITY, sd2 = INFINITY, sd3 = INFINITY;
    int   bk0 = 0, bk1 = 0, bk2 = 0, bk3 = 0;

    #pragma unroll 1
    for (int kt = 0; kt < 8; kt++) {
        f32x4 a = {0.0f, 0.0f, 0.0f, 0.0f};
        const unsigned short* cb = frag + (size_t)(kt * 8) * 512 + lane * 8;
        #pragma unroll
        for (int ks = 0; ks < 4; ks++) {
            const bf16x8 wa = __builtin_bit_cast(bf16x8, *(const ushort8v*)(cb + ks * 1024));
            const bf16x8 wb = __builtin_bit_cast(bf16x8, *(const ushort8v*)(cb + ks * 1024 + 512));
            a = __builtin_amdgcn_mfma_f32_16x16x32_bf16(aA[ks], wa, a, 0, 0, 0);
            a = __builtin_amdgcn_mfma_f32_16x16x32_bf16(aB[ks], wa, a, 0, 0, 0);
            a = __builtin_amdgcn_mfma_f32_16x16x32_bf16(aA[ks], wb, a, 0, 0, 0);
        }
        const float ww = ws[kt * 16 + lr];
        const int   kk = kt * 16 + lr;
        {
            const float d = fmaf(-2.0f, a[0], ww);
            if (d < bd0) { sd0 = bd0; bd0 = d; bk0 = kk; } else if (d < sd0) sd0 = d;
        }
        {
            const float d = fmaf(-2.0f, a[1], ww);
            if (d < bd1) { sd1 = bd1; bd1 = d; bk1 = kk; } else if (d < sd1) sd1 = d;
        }
        {
            const float d = fmaf(-2.0f, a[2], ww);
            if (d < bd2) { sd2 = bd2; bd2 = d; bk2 = kk; } else if (d < sd2) sd2 = d;
        }
        {
            const float d = fmaf(-2.0f, a[3], ww);
            if (d < bd3) { sd3 = bd3; bd3 = d; bk3 = kk; } else if (d < sd3) sd3 = d;
        }
    }

    // ---- cross-lane (16 lanes share a row set) best/2nd reduce ----
    float bd[4] = {bd0, bd1, bd2, bd3};
    float sd[4] = {sd0, sd1, sd2, sd3};
    int   bk[4] = {bk0, bk1, bk2, bk3};
    #pragma unroll
    for (int r = 0; r < 4; r++) {
        #pragma unroll
        for (int m = 1; m < 16; m <<= 1) {
            const float ob = __shfl_xor(bd[r], m, 64);
            const int   ok = __shfl_xor(bk[r], m, 64);
            const float os = __shfl_xor(sd[r], m, 64);
            if (ob < bd[r] || (ob == bd[r] && ok < bk[r])) {
                sd[r] = fminf(bd[r], os);
                bd[r] = ob; bk[r] = ok;
            } else {
                sd[r] = fminf(sd[r], ob);
            }
        }
        if (lr == 0) {
            const int rowL = wave * 16 + lg * 4 + r;   // C layout: row=(lane>>4)*4+reg
            bestk_s[rowL] = ((sd[r] - bd[r]) < TAU) ? (bk[r] | 0x10000) : bk[r];
        }
    }
    __syncthreads();

    // ---- exact repair for near-tie rows (validated round-1 recipe) ----
    if (tid < ROWS_PER_BLOCK) {
        const long long orow = blockRow0 + tid;
        const int bkf = bestk_s[tid];
        if ((bkf & 0x10000) && orow < (long long)n_rows) {
            const float* x = z + orow * D;
            float r0 = __fmul_rn(x[0], x[0]);
            float r1 = __fmul_rn(x[1], x[1]);
            float r2 = __fmul_rn(x[2], x[2]);
            float r3 = __fmul_rn(x[3], x[3]);
            float r4 = __fmul_rn(x[4], x[4]);
            float r5 = __fmul_rn(x[5], x[5]);
            float r6 = __fmul_rn(x[6], x[6]);
            float r7 = __fmul_rn(x[7], x[7]);
            #pragma unroll 1
            for (int i = 8; i < D; i += 8) {
                r0 = __fadd_rn(r0, __fmul_rn(x[i + 0], x[i + 0]));
                r1 = __fadd_rn(r1, __fmul_rn(x[i + 1], x[i + 1]));
                r2 = __fadd_rn(r2, __fmul_rn(x[i + 2], x[i + 2]));
                r3 = __fadd_rn(r3, __fmul_rn(x[i + 3], x[i + 3]));
                r4 = __fadd_rn(r4, __fmul_rn(x[i + 4], x[i + 4]));
                r5 = __fadd_rn(r5, __fmul_rn(x[i + 5], x[i + 5]));
                r6 = __fadd_rn(r6, __fmul_rn(x[i + 6], x[i + 6]));
                r7 = __fadd_rn(r7, __fmul_rn(x[i + 7], x[i + 7]));
            }
            const float a01 = __fadd_rn(r0, r1);
            const float a23 = __fadd_rn(r2, r3);
            const float a45 = __fadd_rn(r4, r5);
            const float a67 = __fadd_rn(r6, r7);
            const float xx = __fadd_rn(__fadd_rn(a01, a23), __fadd_rn(a45, a67));

            float bbd = INFINITY; int bbk = 0;
            #pragma unroll 1
            for (int k = 0; k < K; k++) {
                const float* w = W + (size_t)k * D;
                float acc = 0.0f;
                #pragma unroll
                for (int i = 0; i < D; i++) acc = __fmaf_rn(x[i], w[i], acc);
                const float dd = __fadd_rn(__fsub_rn(xx, __fmul_rn(2.0f, acc)), ws[k]);
                if (dd < bbd) { bbd = dd; bbk = k; }
            }
            bestk_s[tid] = bbk;
        } else {
            bestk_s[tid] = bkf & 0xffff;
        }
    }
    __syncthreads();

    // ---- cooperative coalesced output: 32 lanes per row, W from L1 ----
    const int sub = tid & 31;
    const int grp = tid >> 5;
    float4* out4 = (float4*)out;
    const long long half = (long long)n_rows * (D / 4);
    #pragma unroll 1
    for (int r = grp; r < ROWS_PER_BLOCK; r += 8) {
        const long long orow = blockRow0 + r;
        if (orow >= (long long)n_rows) break;
        const int bkr = bestk_s[r];
        const float4 v = *(const float4*)(W + (size_t)bkr * D + sub * 4);
        const long long o = orow * (D / 4) + sub;
        out4[o] = v;         // z_q
        out4[o + half] = v;  // emb
    }
}

extern "C" void kernel_launch(void* const* d_in, const int* in_sizes, int n_in,
                              void* d_out, int out_size, void* d_ws, size_t ws_size,
                              hipStream_t stream) {
    const float* z = (const float*)d_in[0];
    const float* W = (const float*)d_in[1];
    float* out = (float*)d_out;
    float* ws = (float*)d_ws;
    const int n_rows = in_sizes[0] / D;  // 500000
    vq_prep_kernel<<<dim3(1), dim3(256), 0, stream>>>(W, ws);
    const int blocks = (n_rows + ROWS_PER_BLOCK - 1) / ROWS_PER_BLOCK;
    vq_mfma_kernel<<<dim3(blocks), dim3(256), 0, stream>>>(z, W, ws, out, n_rows);
}

// Round 4
// 810.918 us; speedup vs baseline: 1.0725x; 1.0725x over previous
//
#include <hip/hip_runtime.h>
#include <math.h>

#define D 128
#define K 128
#define ROWS_PER_BLOCK 128
#define TAU 0.05f

typedef __bf16 bf16x8 __attribute__((ext_vector_type(8)));
typedef float f32x4 __attribute__((ext_vector_type(4)));
typedef unsigned short ushort8v __attribute__((ext_vector_type(8)));

__device__ inline unsigned short f2bf(float f) {
    unsigned u = __float_as_uint(f);
    u += 0x7fffu + ((u >> 16) & 1u);   // RNE
    return (unsigned short)(u >> 16);
}
__device__ inline float bf2f(unsigned short h) {
    return __uint_as_float(((unsigned)h) << 16);
}

// ---------------------------------------------------------------------------
// Prep kernel (1 block): exact ww (pairwise-8 recipe) -> ws[0:128)
// plus W as bf16 hi/lo MFMA B-fragments -> ws+128 (64 chunks x 1024 B).
// Chunk c = (kt*4 + ks)*2 + p; lane l holds W[kt*16 + (l&15)][ks*32 + (l>>4)*8 + j]
// Total ws footprint: 512 + 65536 = 66048 B (same as the round-1 PASS).
// ---------------------------------------------------------------------------
__global__ void vq_prep_kernel(const float* __restrict__ W, float* __restrict__ ws)
{
    const int tid = threadIdx.x;

    if (tid < K) {
        const float* w = W + (size_t)tid * D;
        float r0 = __fmul_rn(w[0], w[0]);
        float r1 = __fmul_rn(w[1], w[1]);
        float r2 = __fmul_rn(w[2], w[2]);
        float r3 = __fmul_rn(w[3], w[3]);
        float r4 = __fmul_rn(w[4], w[4]);
        float r5 = __fmul_rn(w[5], w[5]);
        float r6 = __fmul_rn(w[6], w[6]);
        float r7 = __fmul_rn(w[7], w[7]);
        #pragma unroll 1
        for (int i = 8; i < D; i += 8) {
            r0 = __fadd_rn(r0, __fmul_rn(w[i + 0], w[i + 0]));
            r1 = __fadd_rn(r1, __fmul_rn(w[i + 1], w[i + 1]));
            r2 = __fadd_rn(r2, __fmul_rn(w[i + 2], w[i + 2]));
            r3 = __fadd_rn(r3, __fmul_rn(w[i + 3], w[i + 3]));
            r4 = __fadd_rn(r4, __fmul_rn(w[i + 4], w[i + 4]));
            r5 = __fadd_rn(r5, __fmul_rn(w[i + 5], w[i + 5]));
            r6 = __fadd_rn(r6, __fmul_rn(w[i + 6], w[i + 6]));
            r7 = __fadd_rn(r7, __fmul_rn(w[i + 7], w[i + 7]));
        }
        float a01 = __fadd_rn(r0, r1);
        float a23 = __fadd_rn(r2, r3);
        float a45 = __fadd_rn(r4, r5);
        float a67 = __fadd_rn(r6, r7);
        ws[tid] = __fadd_rn(__fadd_rn(a01, a23), __fadd_rn(a45, a67));
    }

    unsigned short* frag = (unsigned short*)(ws + K);
    #pragma unroll 1
    for (int s = tid; s < 64 * 64; s += 256) {
        const int c  = s >> 6;          // chunk 0..63
        const int l  = s & 63;          // lane slot
        const int p  = c & 1;           // 0 = hi plane, 1 = lo plane
        const int ks = (c >> 1) & 3;
        const int kt = c >> 3;
        const int n  = kt * 16 + (l & 15);
        const int k0 = ks * 32 + (l >> 4) * 8;
        const float* wr = W + (size_t)n * D + k0;
        ushort8v o;
        #pragma unroll
        for (int j = 0; j < 8; j++) {
            const float f = wr[j];
            const unsigned short hi = f2bf(f);
            o[j] = (p == 0) ? hi : f2bf(f - bf2f(hi));
        }
        *(ushort8v*)(frag + (size_t)c * 512 + l * 8) = o;
    }
}

// Truncation split of 8 packed floats into bf16 hi/lo planes (cheap bit-ops;
// error ~2^-16 rel, far below TAU/2 -- repair net catches stragglers).
__device__ inline void split8(const float4 v0, const float4 v1, uint4& hi, uint4& lo) {
    const float f[8] = {v0.x, v0.y, v0.z, v0.w, v1.x, v1.y, v1.z, v1.w};
    unsigned h[4], l[4];
    #pragma unroll
    for (int j = 0; j < 4; j++) {
        const unsigned u0 = __float_as_uint(f[2 * j + 0]);
        const unsigned u1 = __float_as_uint(f[2 * j + 1]);
        const unsigned a0 = u0 & 0xffff0000u;
        const unsigned a1 = u1 & 0xffff0000u;
        h[j] = (a0 >> 16) | a1;
        const float r0 = f[2 * j + 0] - __uint_as_float(a0);
        const float r1 = f[2 * j + 1] - __uint_as_float(a1);
        l[j] = (__float_as_uint(r0) >> 16) | (__float_as_uint(r1) & 0xffff0000u);
    }
    hi.x = h[0]; hi.y = h[1]; hi.z = h[2]; hi.w = h[3];
    lo.x = l[0]; lo.y = l[1]; lo.z = l[2]; lo.w = l[3];
}

__device__ inline void upd(float& bd, float& sd, int& bk, float d, int kk) {
    if (d < bd) { sd = bd; bd = d; bk = kk; }
    else if (d < sd) { sd = d; }
}

// ---------------------------------------------------------------------------
// Main kernel: 128 rows/block, 4 waves x 2 tiles of 16 rows. B-frags staged
// in 64 KB LDS (aliased as epilogue scratch after a barrier). Split
// accumulators (even/odd ks) -> 4 independent MFMA chains per wave.
// Near-tie rows repaired cooperatively with the exact validated recipe.
// NOTE: all __syncthreads() are block-uniform (repair trip count nr is read
// from one LDS word after a barrier by every thread).
// ---------------------------------------------------------------------------
__global__ __launch_bounds__(256, 2) void vq_mfma_kernel(
    const float* __restrict__ z,
    const float* __restrict__ W,
    const float* __restrict__ ws,
    float* __restrict__ out,
    int n_rows)
{
    __shared__ uint4 Blds[4096];   // 64 KB: B-frags, later aliased as scratch

    const int tid  = threadIdx.x;
    const int wave = tid >> 6;
    const int lane = tid & 63;
    const int lr   = lane & 15;
    const int lg   = lane >> 4;
    const long long blockRow0 = (long long)blockIdx.x * ROWS_PER_BLOCK;

    // ---- stage all 64 B-frag chunks into LDS (coalesced, 16 uint4/thread) ----
    {
        const uint4* src = (const uint4*)(ws + K);
        #pragma unroll
        for (int j = 0; j < 16; j++)
            Blds[j * 256 + tid] = src[j * 256 + tid];
    }

    // ---- A fragments for 2 row-tiles, truncation split to bf16 hi/lo ----
    bf16x8 aA[2][4], aB[2][4];
    #pragma unroll
    for (int t = 0; t < 2; t++) {
        const long long rowA  = blockRow0 + wave * 32 + t * 16 + lr;
        const long long rowAc = (rowA < (long long)n_rows) ? rowA : (long long)(n_rows - 1);
        const float* zr = z + rowAc * D + lg * 8;
        #pragma unroll
        for (int ks = 0; ks < 4; ks++) {
            const float4 v0 = *(const float4*)(zr + ks * 32);
            const float4 v1 = *(const float4*)(zr + ks * 32 + 4);
            uint4 hi, lo;
            split8(v0, v1, hi, lo);
            aA[t][ks] = __builtin_bit_cast(bf16x8, hi);
            aB[t][ks] = __builtin_bit_cast(bf16x8, lo);
        }
    }

    float bd[2][4], sd[2][4];
    int   bk[2][4];
    #pragma unroll
    for (int t = 0; t < 2; t++)
        #pragma unroll
        for (int r = 0; r < 4; r++) { bd[t][r] = INFINITY; sd[t][r] = INFINITY; bk[t][r] = 0; }

    __syncthreads();   // Blds ready

    // ---- 8 code-tiles x (4 ks x 3 split-term MFMAs) per row-tile ----
    #pragma unroll 2
    for (int kt = 0; kt < 8; kt++) {
        const float ww = ws[kt * 16 + lr];          // 512 B, L1-hot
        f32x4 aE0 = {0.f, 0.f, 0.f, 0.f}, aO0 = {0.f, 0.f, 0.f, 0.f};
        f32x4 aE1 = {0.f, 0.f, 0.f, 0.f}, aO1 = {0.f, 0.f, 0.f, 0.f};
        const uint4* cb = &Blds[kt * 512 + lane];
        #pragma unroll
        for (int ks = 0; ks < 4; ks++) {
            const bf16x8 wa = __builtin_bit_cast(bf16x8, cb[(ks * 2 + 0) * 64]);
            const bf16x8 wb = __builtin_bit_cast(bf16x8, cb[(ks * 2 + 1) * 64]);
            if ((ks & 1) == 0) {
                aE0 = __builtin_amdgcn_mfma_f32_16x16x32_bf16(aA[0][ks], wa, aE0, 0, 0, 0);
                aE0 = __builtin_amdgcn_mfma_f32_16x16x32_bf16(aB[0][ks], wa, aE0, 0, 0, 0);
                aE0 = __builtin_amdgcn_mfma_f32_16x16x32_bf16(aA[0][ks], wb, aE0, 0, 0, 0);
                aE1 = __builtin_amdgcn_mfma_f32_16x16x32_bf16(aA[1][ks], wa, aE1, 0, 0, 0);
                aE1 = __builtin_amdgcn_mfma_f32_16x16x32_bf16(aB[1][ks], wa, aE1, 0, 0, 0);
                aE1 = __builtin_amdgcn_mfma_f32_16x16x32_bf16(aA[1][ks], wb, aE1, 0, 0, 0);
            } else {
                aO0 = __builtin_amdgcn_mfma_f32_16x16x32_bf16(aA[0][ks], wa, aO0, 0, 0, 0);
                aO0 = __builtin_amdgcn_mfma_f32_16x16x32_bf16(aB[0][ks], wa, aO0, 0, 0, 0);
                aO0 = __builtin_amdgcn_mfma_f32_16x16x32_bf16(aA[0][ks], wb, aO0, 0, 0, 0);
                aO1 = __builtin_amdgcn_mfma_f32_16x16x32_bf16(aA[1][ks], wa, aO1, 0, 0, 0);
                aO1 = __builtin_amdgcn_mfma_f32_16x16x32_bf16(aB[1][ks], wa, aO1, 0, 0, 0);
                aO1 = __builtin_amdgcn_mfma_f32_16x16x32_bf16(aA[1][ks], wb, aO1, 0, 0, 0);
            }
        }
        const int kk = kt * 16 + lr;
        #pragma unroll
        for (int j = 0; j < 4; j++) {
            upd(bd[0][j], sd[0][j], bk[0][j], fmaf(-2.0f, aE0[j] + aO0[j], ww), kk);
            upd(bd[1][j], sd[1][j], bk[1][j], fmaf(-2.0f, aE1[j] + aO1[j], ww), kk);
        }
    }

    __syncthreads();   // all waves done with B data; alias LDS as scratch

    int*   bestk_s = (int*)Blds;                    // [128]
    int*   replist = ((int*)Blds) + 128;            // [128]
    float* dscan   = (float*)(((int*)Blds) + 256);  // [128]
    int*   nrep_p  = ((int*)Blds) + 384;
    float* xx_p    = (float*)(((int*)Blds) + 385);

    if (tid == 0) *nrep_p = 0;

    // ---- cross-lane best/2nd reduce (16 lanes per row set) ----
    #pragma unroll
    for (int t = 0; t < 2; t++) {
        #pragma unroll
        for (int r = 0; r < 4; r++) {
            float b  = bd[t][r];
            float s_ = sd[t][r];
            int   k_ = bk[t][r];
            #pragma unroll
            for (int m = 1; m < 16; m <<= 1) {
                const float ob = __shfl_xor(b, m, 64);
                const int   ok = __shfl_xor(k_, m, 64);
                const float os = __shfl_xor(s_, m, 64);
                if (ob < b || (ob == b && ok < k_)) {
                    s_ = fminf(b, os);
                    b = ob; k_ = ok;
                } else {
                    s_ = fminf(s_, ob);
                }
            }
            if (lr == 0) {
                const int rowL = wave * 32 + t * 16 + lg * 4 + r;
                bestk_s[rowL] = ((s_ - b) < TAU) ? (k_ | 0x10000) : k_;
            }
        }
    }
    __syncthreads();

    // ---- collect near-tie rows ----
    if (tid < ROWS_PER_BLOCK) {
        const int v = bestk_s[tid];
        if ((v & 0x10000) && (blockRow0 + tid) < (long long)n_rows) {
            const int idx = atomicAdd(nrep_p, 1);
            if (idx < ROWS_PER_BLOCK) replist[idx] = tid;
        }
    }
    __syncthreads();

    // ---- cooperative exact repair (validated recipe, strict-< ascending) ----
    const int nr = min(*nrep_p, ROWS_PER_BLOCK);
    #pragma unroll 1
    for (int j = 0; j < nr; j++) {
        const int rr = replist[j];
        const float* x = z + (blockRow0 + rr) * (long long)D;
        if (tid == 0) {
            float r0 = __fmul_rn(x[0], x[0]);
            float r1 = __fmul_rn(x[1], x[1]);
            float r2 = __fmul_rn(x[2], x[2]);
            float r3 = __fmul_rn(x[3], x[3]);
            float r4 = __fmul_rn(x[4], x[4]);
            float r5 = __fmul_rn(x[5], x[5]);
            float r6 = __fmul_rn(x[6], x[6]);
            float r7 = __fmul_rn(x[7], x[7]);
            #pragma unroll 1
            for (int i = 8; i < D; i += 8) {
                r0 = __fadd_rn(r0, __fmul_rn(x[i + 0], x[i + 0]));
                r1 = __fadd_rn(r1, __fmul_rn(x[i + 1], x[i + 1]));
                r2 = __fadd_rn(r2, __fmul_rn(x[i + 2], x[i + 2]));
                r3 = __fadd_rn(r3, __fmul_rn(x[i + 3], x[i + 3]));
                r4 = __fadd_rn(r4, __fmul_rn(x[i + 4], x[i + 4]));
                r5 = __fadd_rn(r5, __fmul_rn(x[i + 5], x[i + 5]));
                r6 = __fadd_rn(r6, __fmul_rn(x[i + 6], x[i + 6]));
                r7 = __fadd_rn(r7, __fmul_rn(x[i + 7], x[i + 7]));
            }
            const float a01 = __fadd_rn(r0, r1);
            const float a23 = __fadd_rn(r2, r3);
            const float a45 = __fadd_rn(r4, r5);
            const float a67 = __fadd_rn(r6, r7);
            *xx_p = __fadd_rn(__fadd_rn(a01, a23), __fadd_rn(a45, a67));
        }
        __syncthreads();
        if (tid < K) {
            const float* w = W + (size_t)tid * D;
            float acc = 0.0f;
            #pragma unroll
            for (int i = 0; i < D; i++) acc = __fmaf_rn(x[i], w[i], acc);
            dscan[tid] = __fadd_rn(__fsub_rn(*xx_p, __fmul_rn(2.0f, acc)), ws[tid]);
        }
        __syncthreads();
        if (tid == 0) {
            float bbd = INFINITY; int bbk = 0;
            #pragma unroll 1
            for (int k = 0; k < K; k++) {
                const float dd = dscan[k];
                if (dd < bbd) { bbd = dd; bbk = k; }
            }
            bestk_s[rr] = bbk;
        }
        __syncthreads();
    }

    // ---- cooperative coalesced output: 32 lanes per row, W from L1 ----
    const int sub = tid & 31;
    const int grp = tid >> 5;
    float4* out4 = (float4*)out;
    const long long half = (long long)n_rows * (D / 4);
    #pragma unroll 2
    for (int r = grp; r < ROWS_PER_BLOCK; r += 8) {
        const long long orow = blockRow0 + r;
        if (orow >= (long long)n_rows) break;
        const int bkr = bestk_s[r] & 0xffff;
        const float4 v = *(const float4*)(W + (size_t)bkr * D + sub * 4);
        const long long o = orow * (D / 4) + sub;
        out4[o] = v;         // z_q
        out4[o + half] = v;  // emb
    }
}

extern "C" void kernel_launch(void* const* d_in, const int* in_sizes, int n_in,
                              void* d_out, int out_size, void* d_ws, size_t ws_size,
                              hipStream_t stream) {
    const float* z = (const float*)d_in[0];
    const float* W = (const float*)d_in[1];
    float* out = (float*)d_out;
    float* ws = (float*)d_ws;
    const int n_rows = in_sizes[0] / D;  // 500000
    vq_prep_kernel<<<dim3(1), dim3(256), 0, stream>>>(W, ws);
    const int blocks = (n_rows + ROWS_PER_BLOCK - 1) / ROWS_PER_BLOCK;
    vq_mfma_kernel<<<dim3(blocks), dim3(256), 0, stream>>>(z, W, ws, out, n_rows);
}